// Round 18
// baseline (291.322 us; speedup 1.0000x reference)
//
#include <hip/hip_runtime.h>
#include <math.h>

#define NMOL  1024
#define N     128          // atoms per molecule (Schur-reduced SPD system size)
#define NELEM 10
#define BLOCK 256          // 2 molecules per block: waves 0,1 = mol0; waves 2,3 = mol1
#define PW    8            // panel width
#define NPAN  16           // 128 / 8
#define PSTR  12           // panel-column buffer row stride (floats)
#define USTR  132          // U-panel row stride

typedef __attribute__((ext_vector_type(4))) float f4;

// R17 (137 us: fused [GEMM(p-1)+stage(p)+A(p)] | [B(p)], parity-dbuf P,
// rsqrt A-gen, no breaks) + fused single-barrier back-substitution:
// iteration pb = [apply x(pb+1) from pair-(pb+1) registers (wave
// (pb+1)&1, lanes<4pb+4); solve-lanes 4pb..4pb+3 keep updated rhs IN
// REGISTERS and run a 4-lane shuffle back-solve of panel pb (Phase-A
// style), writing sx; other lanes persist rhs] -> 1 barrier/iter
// (32 -> 16 barriers), the 4-thread serial solve + 8 divides gone
// (DinvAll multiplies, storage verified spill-free in R16).
// Sequence: solve(15); {upd(15),solve(14)}; ...; {upd(1),solve(0)}
// == the old schedule. NO mid-loop break anywhere (breaks demote the
// Ar tiles to scratch: R2/R13/R14 spilled ~0.5 GB).

__global__ __launch_bounds__(BLOCK, 2) void ceq_solve_kernel(
    const float* __restrict__ eneg,
    const float* __restrict__ positions,
    const float* __restrict__ node_attrs,
    const float* __restrict__ hardness,
    const float* __restrict__ total_charge,
    const int*   __restrict__ atomic_numbers,
    float* __restrict__ out)
{
    __shared__ __align__(16) float P[2][2][N * PSTR];      // [mol][panel-parity buf]
    __shared__ __align__(16) float Up[2][PW * USTR];       // U rows (D*L^T)
    __shared__ __align__(16) float Ublk[2][NPAN][PW][PW];  // 8x8 diag blocks (L\U packed)
    __shared__ float DinvAll[2][NPAN][PW];                 // 1/diag per panel
    __shared__ float Dd[2][PW];                            // diag of current panel
    __shared__ float rhsY[2][N], rhsZ[2][N];
    __shared__ float sxY[2][N], sxZ[2][N];
    __shared__ float px[2][N], py[2][N], pz[2][N], sg[2][N], dgv[2][N];
    __shared__ float lamS[2];

    const int tid  = threadIdx.x;
    const int lane = tid & 63;
    const int g    = tid >> 7;        // molecule within block
    const int gt   = tid & 127;       // thread within molecule
    const int wv   = (tid >> 6) & 1;  // wave within molecule
    const int r0   = 2 * lane;
    const int r1   = r0 + 1;
    const int mol  = 2 * blockIdx.x + g;
    const int base = mol * N;

    // ---- per-atom precompute (thread gt loads atom gt of its molecule) ----
    {
        const int i = gt;
        const int Z = atomic_numbers[base + i];
        const float rad = 0.3f + 0.02f * (float)Z;
        sg[g][i] = 2.0f * rad * rad;           // 2*sigma: rsqrt(sg_i+sg_j) = 1/(sqrt2*gamma)
        const float* na = node_attrs + (size_t)(base + i) * NELEM;
        float best = na[0]; int bi = 0;
        #pragma unroll
        for (int e = 1; e < NELEM; ++e) {
            float v = na[e];
            if (v > best) { best = v; bi = e; }     // first-max = jnp.argmax
        }
        dgv[g][i] = hardness[bi] + 0.5641895835477563f / rad;  // h + 1/(sqrt(pi) r)
        const float* p = positions + (size_t)(base + i) * 3;
        px[g][i] = p[0]; py[g][i] = p[1]; pz[g][i] = p[2];
        rhsY[g][i] = -eneg[base + i];   // A y = b
        rhsZ[g][i] = 1.0f;              // A z = 1
    }
    __syncthreads();

    // ---- fill register tiles: rows r0,r1; f4 c -> cols 16*(c>>1)+8*wv+4*(c&1) ----
    f4 Ar0[16], Ar1[16];
    {
        const float x0 = px[g][r0], y0 = py[g][r0], z0 = pz[g][r0];
        const float s0 = sg[g][r0], d0 = dgv[g][r0];
        const float x1 = px[g][r1], y1 = py[g][r1], z1 = pz[g][r1];
        const float s1 = sg[g][r1], d1 = dgv[g][r1];
        #pragma unroll
        for (int c = 0; c < 16; ++c) {
            const int jb = 16 * (c >> 1) + 8 * wv + 4 * (c & 1);
            f4 v0, v1;
            #pragma unroll
            for (int e = 0; e < 4; ++e) {
                const int j = jb + e;
                float a0, a1;
                if (j == r0) a0 = d0;
                else {
                    const float dx = x0 - px[g][j], dy = y0 - py[g][j], dz = z0 - pz[g][j];
                    const float d2 = dx * dx + dy * dy + dz * dz;
                    const float rd = rsqrtf(d2);              // 1/d
                    const float rg = rsqrtf(s0 + sg[g][j]);   // 1/(sqrt2*gamma)
                    a0 = erff(d2 * rd * rg) * rd;             // erf(d/(sqrt2 g))/d
                }
                if (j == r1) a1 = d1;
                else {
                    const float dx = x1 - px[g][j], dy = y1 - py[g][j], dz = z1 - pz[g][j];
                    const float d2 = dx * dx + dy * dy + dz * dz;
                    const float rd = rsqrtf(d2);
                    const float rg = rsqrtf(s1 + sg[g][j]);
                    a1 = erff(d2 * rd * rg) * rd;
                }
                ((float*)&v0)[e] = a0;
                ((float*)&v1)[e] = a1;
            }
            Ar0[c] = v0;
            Ar1[c] = v1;
        }
    }

    // ================= blocked LDL^T, A register-resident =================
    for (int p = 0; p < NPAN; ++p) {
        const int k0 = PW * p;
        const int q  = (p >> 1) & 7;         // owner wave's local pair index
        float* Pc = &P[g][p & 1][0];

        // ==== fused phase: [reload(p-1) + GEMM(p-1)] then [stage(p) + A(p)] ====
        if (p > 0) {
            const int pm = p - 1;
            float* Pp = &P[g][pm & 1][0];
            if (lane >= 4 * pm && lane < 4 * pm + 4) {   // panel-pm rows: pull U rows
                const int u0 = r0 - PW * pm, u1 = u0 + 1;
                #pragma unroll
                for (int c = 0; c < 16; ++c) {
                    const int t  = 2 * (c >> 1) + wv;
                    const int gc = 4 * (c >> 1) + 2 * wv + (c & 1);
                    if (t > pm) {
                        Ar0[c] = *(const f4*)&Up[g][u0 * USTR + 4 * gc];
                        Ar1[c] = *(const f4*)&Up[g][u1 * USTR + 4 * gc];
                    }
                }
            }
            const bool hasmat = (14 + wv) > pm;
            if (hasmat && lane >= 4 * pm + 4) {           // rows >= k0(pm)+8
                float lA0[PW], lA1[PW];
                {
                    f4 a = *(const f4*)&Pp[r0 * PSTR], b = *(const f4*)&Pp[r0 * PSTR + 4];
                    lA0[0]=a.x; lA0[1]=a.y; lA0[2]=a.z; lA0[3]=a.w;
                    lA0[4]=b.x; lA0[5]=b.y; lA0[6]=b.z; lA0[7]=b.w;
                    f4 c2 = *(const f4*)&Pp[r1 * PSTR], d2 = *(const f4*)&Pp[r1 * PSTR + 4];
                    lA1[0]=c2.x; lA1[1]=c2.y; lA1[2]=c2.z; lA1[3]=c2.w;
                    lA1[4]=d2.x; lA1[5]=d2.y; lA1[6]=d2.z; lA1[7]=d2.w;
                }
                #pragma unroll
                for (int c = 0; c < 16; ++c) {
                    const int t  = 2 * (c >> 1) + wv;
                    const int gc = 4 * (c >> 1) + 2 * wv + (c & 1);
                    if (t > pm) {
                        f4 acc0 = Ar0[c], acc1 = Ar1[c];
                        #pragma unroll
                        for (int u = 0; u < PW; ++u) {
                            const f4 uv = *(const f4*)&Up[g][u * USTR + 4 * gc]; // broadcast
                            acc0 -= uv * lA0[u];
                            acc1 -= uv * lA1[u];
                        }
                        Ar0[c] = acc0; Ar1[c] = acc1;
                    }
                }
            }
        }
        // stage(p) + Phase A(p): wave p&1, post-GEMM register values (thread-local)
        if (wv == (p & 1) && lane >= 4 * p) {
            f4 a00, a01, a10, a11;
            switch (q) {
                case 0:  a00 = Ar0[0];  a01 = Ar0[1];  a10 = Ar1[0];  a11 = Ar1[1];  break;
                case 1:  a00 = Ar0[2];  a01 = Ar0[3];  a10 = Ar1[2];  a11 = Ar1[3];  break;
                case 2:  a00 = Ar0[4];  a01 = Ar0[5];  a10 = Ar1[4];  a11 = Ar1[5];  break;
                case 3:  a00 = Ar0[6];  a01 = Ar0[7];  a10 = Ar1[6];  a11 = Ar1[7];  break;
                case 4:  a00 = Ar0[8];  a01 = Ar0[9];  a10 = Ar1[8];  a11 = Ar1[9];  break;
                case 5:  a00 = Ar0[10]; a01 = Ar0[11]; a10 = Ar1[10]; a11 = Ar1[11]; break;
                case 6:  a00 = Ar0[12]; a01 = Ar0[13]; a10 = Ar1[12]; a11 = Ar1[13]; break;
                default: a00 = Ar0[14]; a01 = Ar0[15]; a10 = Ar1[14]; a11 = Ar1[15]; break;
            }
            if (lane >= 4 * p + 4) {          // rows >= k0+8: stage for phase B
                *(f4*)&Pc[r0 * PSTR + 0] = a00; *(f4*)&Pc[r0 * PSTR + 4] = a01;
                *(f4*)&Pc[r1 * PSTR + 0] = a10; *(f4*)&Pc[r1 * PSTR + 4] = a11;
            } else {                          // Phase A: 4-lane 8x8 LU + fused rhs
                float u0[PW] = { a00.x, a00.y, a00.z, a00.w, a01.x, a01.y, a01.z, a01.w };
                float u1[PW] = { a10.x, a10.y, a10.z, a10.w, a11.x, a11.y, a11.z, a11.w };
                float ry0 = rhsY[g][r0], rz0 = rhsZ[g][r0];
                float ry1 = rhsY[g][r1], rz1 = rhsZ[g][r1];
                const int rl = lane - 4 * p;  // 0..3: rows 2rl, 2rl+1 of the panel
                #pragma unroll
                for (int kk = 0; kk < PW; ++kk) {
                    const int src = 4 * p + (kk >> 1);
                    float pr[PW];
                    #pragma unroll
                    for (int j = kk; j < PW; ++j)
                        pr[j] = __shfl((kk & 1) ? u1[j] : u0[j], src);
                    const float cY = __shfl((kk & 1) ? ry1 : ry0, src);
                    const float cZ = __shfl((kk & 1) ? rz1 : rz0, src);
                    const float dinv = 1.0f / pr[kk];
                    if (2 * rl > kk) {
                        const float m = u0[kk] * dinv; u0[kk] = m;
                        #pragma unroll
                        for (int j = kk + 1; j < PW; ++j) u0[j] -= m * pr[j];
                        ry0 -= m * cY; rz0 -= m * cZ;
                    }
                    if (2 * rl + 1 > kk) {
                        const float m = u1[kk] * dinv; u1[kk] = m;
                        #pragma unroll
                        for (int j = kk + 1; j < PW; ++j) u1[j] -= m * pr[j];
                        ry1 -= m * cY; rz1 -= m * cZ;
                    }
                    if (rl == (kk >> 1)) { DinvAll[g][p][kk] = dinv; Dd[g][kk] = pr[kk]; }
                }
                f4 w0 = { u0[0], u0[1], u0[2], u0[3] }, w1 = { u0[4], u0[5], u0[6], u0[7] };
                *(f4*)&Ublk[g][p][2 * rl][0] = w0; *(f4*)&Ublk[g][p][2 * rl][4] = w1;
                f4 w2 = { u1[0], u1[1], u1[2], u1[3] }, w3 = { u1[4], u1[5], u1[6], u1[7] };
                *(f4*)&Ublk[g][p][2 * rl + 1][0] = w2; *(f4*)&Ublk[g][p][2 * rl + 1][4] = w3;
                rhsY[g][r0] = ry0; rhsZ[g][r0] = rz0;
                rhsY[g][r1] = ry1; rhsZ[g][r1] = rz1;
            }
        }
        __syncthreads();

        // ==== Phase B(p): all 128 threads, one trailing row each ====
        const int nb = (N - PW) - k0;         // 120 - 8p trailing rows
        if (gt < nb) {
            const int i = k0 + PW + gt;
            f4 a = *(const f4*)&Pc[i * PSTR], b = *(const f4*)&Pc[i * PSTR + 4];
            float av[PW] = { a.x, a.y, a.z, a.w, b.x, b.y, b.z, b.w };
            float m[PW];
            #pragma unroll
            for (int j = 0; j < PW; ++j) {
                float acc = av[j];
                #pragma unroll
                for (int t = 0; t < j; ++t) acc -= m[t] * Ublk[g][p][t][j];
                m[j] = acc * DinvAll[g][p][j];
            }
            f4 ma = { m[0], m[1], m[2], m[3] }, mb = { m[4], m[5], m[6], m[7] };
            *(f4*)&Pc[i * PSTR]     = ma;     // multipliers: GEMM lA operand
            *(f4*)&Pc[i * PSTR + 4] = mb;
            #pragma unroll
            for (int u = 0; u < PW; ++u) Up[g][u * USTR + i] = m[u] * Dd[g][u];
            float ry = rhsY[g][i], rz = rhsZ[g][i];
            #pragma unroll
            for (int t = 0; t < PW; ++t) {
                ry -= m[t] * rhsY[g][k0 + t];
                rz -= m[t] * rhsZ[g][k0 + t];
            }
            rhsY[g][i] = ry; rhsZ[g][i] = rz;
        }
        __syncthreads();
    }

    // ====== fused back substitution: 1 barrier/iter ======
    // iteration pb: wave (pb+1)&1 applies x(pb+1) from its pair-(pb+1)
    // registers; solve-lanes (4pb..4pb+3) keep updated rhs in registers
    // and shuffle-solve panel pb; other lanes persist rhs to LDS.
    for (int pb = NPAN - 1; pb >= 0; --pb) {
        const int k0 = PW * pb;
        if (wv == ((pb + 1) & 1) && lane < 4 * pb + 4) {
            float yy0 = rhsY[g][r0], yy1 = rhsY[g][r1];
            float zz0 = rhsZ[g][r0], zz1 = rhsZ[g][r1];
            if (pb < NPAN - 1) {                  // apply x(pb+1): pair pb+1 regs
                f4 a00, a01, a10, a11;
                switch ((pb + 1) >> 1) {
                    case 0:  a00 = Ar0[0];  a01 = Ar0[1];  a10 = Ar1[0];  a11 = Ar1[1];  break;
                    case 1:  a00 = Ar0[2];  a01 = Ar0[3];  a10 = Ar1[2];  a11 = Ar1[3];  break;
                    case 2:  a00 = Ar0[4];  a01 = Ar0[5];  a10 = Ar1[4];  a11 = Ar1[5];  break;
                    case 3:  a00 = Ar0[6];  a01 = Ar0[7];  a10 = Ar1[6];  a11 = Ar1[7];  break;
                    case 4:  a00 = Ar0[8];  a01 = Ar0[9];  a10 = Ar1[8];  a11 = Ar1[9];  break;
                    case 5:  a00 = Ar0[10]; a01 = Ar0[11]; a10 = Ar1[10]; a11 = Ar1[11]; break;
                    case 6:  a00 = Ar0[12]; a01 = Ar0[13]; a10 = Ar1[12]; a11 = Ar1[13]; break;
                    default: a00 = Ar0[14]; a01 = Ar0[15]; a10 = Ar1[14]; a11 = Ar1[15]; break;
                }
                const int ku = k0 + PW;
                yy0 -= a00.x*sxY[g][ku]   + a00.y*sxY[g][ku+1] + a00.z*sxY[g][ku+2] + a00.w*sxY[g][ku+3]
                     + a01.x*sxY[g][ku+4] + a01.y*sxY[g][ku+5] + a01.z*sxY[g][ku+6] + a01.w*sxY[g][ku+7];
                yy1 -= a10.x*sxY[g][ku]   + a10.y*sxY[g][ku+1] + a10.z*sxY[g][ku+2] + a10.w*sxY[g][ku+3]
                     + a11.x*sxY[g][ku+4] + a11.y*sxY[g][ku+5] + a11.z*sxY[g][ku+6] + a11.w*sxY[g][ku+7];
                zz0 -= a00.x*sxZ[g][ku]   + a00.y*sxZ[g][ku+1] + a00.z*sxZ[g][ku+2] + a00.w*sxZ[g][ku+3]
                     + a01.x*sxZ[g][ku+4] + a01.y*sxZ[g][ku+5] + a01.z*sxZ[g][ku+6] + a01.w*sxZ[g][ku+7];
                zz1 -= a10.x*sxZ[g][ku]   + a10.y*sxZ[g][ku+1] + a10.z*sxZ[g][ku+2] + a10.w*sxZ[g][ku+3]
                     + a11.x*sxZ[g][ku+4] + a11.y*sxZ[g][ku+5] + a11.z*sxZ[g][ku+6] + a11.w*sxZ[g][ku+7];
            }
            if (lane >= 4 * pb) {                 // 4-lane shuffle back-solve
                const int u0 = r0 - k0;           // 0,2,4,6
                #pragma unroll
                for (int kk = PW - 1; kk >= 0; --kk) {
                    const int src = 4 * pb + (kk >> 1);
                    const float di = DinvAll[g][pb][kk];
                    const float cy = ((kk & 1) ? yy1 : yy0) * di;
                    const float cz = ((kk & 1) ? zz1 : zz0) * di;
                    const float xky = __shfl(cy, src);
                    const float xkz = __shfl(cz, src);
                    if (lane == src) {
                        if (kk & 1) { sxY[g][r1] = xky; sxZ[g][r1] = xkz; }
                        else        { sxY[g][r0] = xky; sxZ[g][r0] = xkz; }
                    }
                    if (u0 < kk) {
                        const float u = Ublk[g][pb][u0][kk];
                        yy0 -= u * xky; zz0 -= u * xkz;
                    }
                    if (u0 + 1 < kk) {
                        const float u = Ublk[g][pb][u0 + 1][kk];
                        yy1 -= u * xky; zz1 -= u * xkz;
                    }
                }
            } else {                              // persist updated rhs
                rhsY[g][r0] = yy0; rhsY[g][r1] = yy1;
                rhsZ[g][r0] = zz0; rhsZ[g][r1] = zz1;
            }
        }
        __syncthreads();
    }

    // ---- Schur closure: lambda = (1'y - Q)/(1'z - 1); q = y - lambda z ----
    if (wv == 0) {
        float vY = sxY[g][lane] + sxY[g][lane + 64];
        float vZ = sxZ[g][lane] + sxZ[g][lane + 64];
        #pragma unroll
        for (int off = 32; off; off >>= 1) {
            vY += __shfl_xor(vY, off);
            vZ += __shfl_xor(vZ, off);
        }
        if (lane == 0) lamS[g] = (vY - total_charge[mol]) / (vZ - 1.0f);
    }
    __syncthreads();
    out[base + gt] = sxY[g][gt] - lamS[g] * sxZ[g][gt];
}

extern "C" void kernel_launch(void* const* d_in, const int* in_sizes, int n_in,
                              void* d_out, int out_size, void* d_ws, size_t ws_size,
                              hipStream_t stream) {
    const float* eneg           = (const float*)d_in[0];
    const float* positions      = (const float*)d_in[1];
    const float* node_attrs     = (const float*)d_in[2];
    const float* hardness       = (const float*)d_in[3];
    const float* total_charge   = (const float*)d_in[4];
    // d_in[5] = batch (unused: equal-sized sorted molecules)
    const int*   atomic_numbers = (const int*)d_in[6];
    float* out = (float*)d_out;

    ceq_solve_kernel<<<NMOL / 2, BLOCK, 0, stream>>>(
        eneg, positions, node_attrs, hardness, total_charge, atomic_numbers, out);
}

// Round 19
// 190.310 us; speedup vs baseline: 1.5308x; 1.5308x over previous
//
#include <hip/hip_runtime.h>
#include <math.h>

#define NMOL  1024
#define N     128          // atoms per molecule (Schur-reduced SPD system size)
#define NELEM 10
#define BLOCK 256          // 2 molecules per block: waves 0,1 = mol0; waves 2,3 = mol1
#define PW    8            // panel width
#define NPAN  16           // 128 / 8
#define PSTR  12           // panel-column buffer row stride (floats)
#define USTR  132          // U-panel row stride

typedef __attribute__((ext_vector_type(4))) float f4;

// R17 (verified best 137 us: fused [GEMM(p-1)+stage(p)+A(p)] | [B(p)],
// parity-dbuf P, rsqrt A-gen, no breaks) + DinvAll reciprocals (stored by
// Phase A; spill-free in R16 AND R18) so Phase B and the back-sub solve
// use multiplies -- removes 8 serial fp32 divides x 16 panels from the
// 4-thread solve's critical path. Everything else byte-identical to R17.
// Hard-won constraints honored: NO mid-loop break (R2/R13/R14 spilled
// ~0.5 GB); no narrow dependent-chain phases with in-chain LDS reads
// (R18: 4-lane shuffle back-solve -75%); phase-local carried state kept
// ~0 on top of the 128-reg Ar tiles (R12 spill).

__global__ __launch_bounds__(BLOCK, 2) void ceq_solve_kernel(
    const float* __restrict__ eneg,
    const float* __restrict__ positions,
    const float* __restrict__ node_attrs,
    const float* __restrict__ hardness,
    const float* __restrict__ total_charge,
    const int*   __restrict__ atomic_numbers,
    float* __restrict__ out)
{
    __shared__ __align__(16) float P[2][2][N * PSTR];      // [mol][panel-parity buf]
    __shared__ __align__(16) float Up[2][PW * USTR];       // U rows (D*L^T)
    __shared__ __align__(16) float Ublk[2][NPAN][PW][PW];  // 8x8 diag blocks (L\U packed)
    __shared__ float DinvAll[2][NPAN][PW];                 // 1/diag per panel
    __shared__ float Dd[2][PW];                            // diag of current panel
    __shared__ float rhsY[2][N], rhsZ[2][N];
    __shared__ float sxY[2][N], sxZ[2][N];
    __shared__ float px[2][N], py[2][N], pz[2][N], sg[2][N], dgv[2][N];
    __shared__ float lamS[2];

    const int tid  = threadIdx.x;
    const int lane = tid & 63;
    const int g    = tid >> 7;        // molecule within block
    const int gt   = tid & 127;       // thread within molecule
    const int wv   = (tid >> 6) & 1;  // wave within molecule
    const int r0   = 2 * lane;
    const int r1   = r0 + 1;
    const int mol  = 2 * blockIdx.x + g;
    const int base = mol * N;

    // ---- per-atom precompute (thread gt loads atom gt of its molecule) ----
    {
        const int i = gt;
        const int Z = atomic_numbers[base + i];
        const float rad = 0.3f + 0.02f * (float)Z;
        sg[g][i] = 2.0f * rad * rad;           // 2*sigma: rsqrt(sg_i+sg_j) = 1/(sqrt2*gamma)
        const float* na = node_attrs + (size_t)(base + i) * NELEM;
        float best = na[0]; int bi = 0;
        #pragma unroll
        for (int e = 1; e < NELEM; ++e) {
            float v = na[e];
            if (v > best) { best = v; bi = e; }     // first-max = jnp.argmax
        }
        dgv[g][i] = hardness[bi] + 0.5641895835477563f / rad;  // h + 1/(sqrt(pi) r)
        const float* p = positions + (size_t)(base + i) * 3;
        px[g][i] = p[0]; py[g][i] = p[1]; pz[g][i] = p[2];
        rhsY[g][i] = -eneg[base + i];   // A y = b
        rhsZ[g][i] = 1.0f;              // A z = 1
    }
    __syncthreads();

    // ---- fill register tiles: rows r0,r1; f4 c -> cols 16*(c>>1)+8*wv+4*(c&1) ----
    f4 Ar0[16], Ar1[16];
    {
        const float x0 = px[g][r0], y0 = py[g][r0], z0 = pz[g][r0];
        const float s0 = sg[g][r0], d0 = dgv[g][r0];
        const float x1 = px[g][r1], y1 = py[g][r1], z1 = pz[g][r1];
        const float s1 = sg[g][r1], d1 = dgv[g][r1];
        #pragma unroll
        for (int c = 0; c < 16; ++c) {
            const int jb = 16 * (c >> 1) + 8 * wv + 4 * (c & 1);
            f4 v0, v1;
            #pragma unroll
            for (int e = 0; e < 4; ++e) {
                const int j = jb + e;
                float a0, a1;
                if (j == r0) a0 = d0;
                else {
                    const float dx = x0 - px[g][j], dy = y0 - py[g][j], dz = z0 - pz[g][j];
                    const float d2 = dx * dx + dy * dy + dz * dz;
                    const float rd = rsqrtf(d2);              // 1/d
                    const float rg = rsqrtf(s0 + sg[g][j]);   // 1/(sqrt2*gamma)
                    a0 = erff(d2 * rd * rg) * rd;             // erf(d/(sqrt2 g))/d
                }
                if (j == r1) a1 = d1;
                else {
                    const float dx = x1 - px[g][j], dy = y1 - py[g][j], dz = z1 - pz[g][j];
                    const float d2 = dx * dx + dy * dy + dz * dz;
                    const float rd = rsqrtf(d2);
                    const float rg = rsqrtf(s1 + sg[g][j]);
                    a1 = erff(d2 * rd * rg) * rd;
                }
                ((float*)&v0)[e] = a0;
                ((float*)&v1)[e] = a1;
            }
            Ar0[c] = v0;
            Ar1[c] = v1;
        }
    }

    // ================= blocked LDL^T, A register-resident =================
    for (int p = 0; p < NPAN; ++p) {
        const int k0 = PW * p;
        const int q  = (p >> 1) & 7;         // owner wave's local pair index
        float* Pc = &P[g][p & 1][0];

        // ==== fused phase: [reload(p-1) + GEMM(p-1)] then [stage(p) + A(p)] ====
        if (p > 0) {
            const int pm = p - 1;
            float* Pp = &P[g][pm & 1][0];
            if (lane >= 4 * pm && lane < 4 * pm + 4) {   // panel-pm rows: pull U rows
                const int u0 = r0 - PW * pm, u1 = u0 + 1;
                #pragma unroll
                for (int c = 0; c < 16; ++c) {
                    const int t  = 2 * (c >> 1) + wv;
                    const int gc = 4 * (c >> 1) + 2 * wv + (c & 1);
                    if (t > pm) {
                        Ar0[c] = *(const f4*)&Up[g][u0 * USTR + 4 * gc];
                        Ar1[c] = *(const f4*)&Up[g][u1 * USTR + 4 * gc];
                    }
                }
            }
            const bool hasmat = (14 + wv) > pm;
            if (hasmat && lane >= 4 * pm + 4) {           // rows >= k0(pm)+8
                float lA0[PW], lA1[PW];
                {
                    f4 a = *(const f4*)&Pp[r0 * PSTR], b = *(const f4*)&Pp[r0 * PSTR + 4];
                    lA0[0]=a.x; lA0[1]=a.y; lA0[2]=a.z; lA0[3]=a.w;
                    lA0[4]=b.x; lA0[5]=b.y; lA0[6]=b.z; lA0[7]=b.w;
                    f4 c2 = *(const f4*)&Pp[r1 * PSTR], d2 = *(const f4*)&Pp[r1 * PSTR + 4];
                    lA1[0]=c2.x; lA1[1]=c2.y; lA1[2]=c2.z; lA1[3]=c2.w;
                    lA1[4]=d2.x; lA1[5]=d2.y; lA1[6]=d2.z; lA1[7]=d2.w;
                }
                #pragma unroll
                for (int c = 0; c < 16; ++c) {
                    const int t  = 2 * (c >> 1) + wv;
                    const int gc = 4 * (c >> 1) + 2 * wv + (c & 1);
                    if (t > pm) {
                        f4 acc0 = Ar0[c], acc1 = Ar1[c];
                        #pragma unroll
                        for (int u = 0; u < PW; ++u) {
                            const f4 uv = *(const f4*)&Up[g][u * USTR + 4 * gc]; // broadcast
                            acc0 -= uv * lA0[u];
                            acc1 -= uv * lA1[u];
                        }
                        Ar0[c] = acc0; Ar1[c] = acc1;
                    }
                }
            }
        }
        // stage(p) + Phase A(p): wave p&1, post-GEMM register values (thread-local)
        if (wv == (p & 1) && lane >= 4 * p) {
            f4 a00, a01, a10, a11;
            switch (q) {
                case 0:  a00 = Ar0[0];  a01 = Ar0[1];  a10 = Ar1[0];  a11 = Ar1[1];  break;
                case 1:  a00 = Ar0[2];  a01 = Ar0[3];  a10 = Ar1[2];  a11 = Ar1[3];  break;
                case 2:  a00 = Ar0[4];  a01 = Ar0[5];  a10 = Ar1[4];  a11 = Ar1[5];  break;
                case 3:  a00 = Ar0[6];  a01 = Ar0[7];  a10 = Ar1[6];  a11 = Ar1[7];  break;
                case 4:  a00 = Ar0[8];  a01 = Ar0[9];  a10 = Ar1[8];  a11 = Ar1[9];  break;
                case 5:  a00 = Ar0[10]; a01 = Ar0[11]; a10 = Ar1[10]; a11 = Ar1[11]; break;
                case 6:  a00 = Ar0[12]; a01 = Ar0[13]; a10 = Ar1[12]; a11 = Ar1[13]; break;
                default: a00 = Ar0[14]; a01 = Ar0[15]; a10 = Ar1[14]; a11 = Ar1[15]; break;
            }
            if (lane >= 4 * p + 4) {          // rows >= k0+8: stage for phase B
                *(f4*)&Pc[r0 * PSTR + 0] = a00; *(f4*)&Pc[r0 * PSTR + 4] = a01;
                *(f4*)&Pc[r1 * PSTR + 0] = a10; *(f4*)&Pc[r1 * PSTR + 4] = a11;
            } else {                          // Phase A: 4-lane 8x8 LU + fused rhs
                float u0[PW] = { a00.x, a00.y, a00.z, a00.w, a01.x, a01.y, a01.z, a01.w };
                float u1[PW] = { a10.x, a10.y, a10.z, a10.w, a11.x, a11.y, a11.z, a11.w };
                float ry0 = rhsY[g][r0], rz0 = rhsZ[g][r0];
                float ry1 = rhsY[g][r1], rz1 = rhsZ[g][r1];
                const int rl = lane - 4 * p;  // 0..3: rows 2rl, 2rl+1 of the panel
                #pragma unroll
                for (int kk = 0; kk < PW; ++kk) {
                    const int src = 4 * p + (kk >> 1);
                    float pr[PW];
                    #pragma unroll
                    for (int j = kk; j < PW; ++j)
                        pr[j] = __shfl((kk & 1) ? u1[j] : u0[j], src);
                    const float cY = __shfl((kk & 1) ? ry1 : ry0, src);
                    const float cZ = __shfl((kk & 1) ? rz1 : rz0, src);
                    const float dinv = 1.0f / pr[kk];
                    if (2 * rl > kk) {
                        const float m = u0[kk] * dinv; u0[kk] = m;
                        #pragma unroll
                        for (int j = kk + 1; j < PW; ++j) u0[j] -= m * pr[j];
                        ry0 -= m * cY; rz0 -= m * cZ;
                    }
                    if (2 * rl + 1 > kk) {
                        const float m = u1[kk] * dinv; u1[kk] = m;
                        #pragma unroll
                        for (int j = kk + 1; j < PW; ++j) u1[j] -= m * pr[j];
                        ry1 -= m * cY; rz1 -= m * cZ;
                    }
                    if (rl == (kk >> 1)) { DinvAll[g][p][kk] = dinv; Dd[g][kk] = pr[kk]; }
                }
                f4 w0 = { u0[0], u0[1], u0[2], u0[3] }, w1 = { u0[4], u0[5], u0[6], u0[7] };
                *(f4*)&Ublk[g][p][2 * rl][0] = w0; *(f4*)&Ublk[g][p][2 * rl][4] = w1;
                f4 w2 = { u1[0], u1[1], u1[2], u1[3] }, w3 = { u1[4], u1[5], u1[6], u1[7] };
                *(f4*)&Ublk[g][p][2 * rl + 1][0] = w2; *(f4*)&Ublk[g][p][2 * rl + 1][4] = w3;
                rhsY[g][r0] = ry0; rhsZ[g][r0] = rz0;
                rhsY[g][r1] = ry1; rhsZ[g][r1] = rz1;
            }
        }
        __syncthreads();

        // ==== Phase B(p): all 128 threads, one trailing row each ====
        const int nb = (N - PW) - k0;         // 120 - 8p trailing rows
        if (gt < nb) {
            const int i = k0 + PW + gt;
            f4 a = *(const f4*)&Pc[i * PSTR], b = *(const f4*)&Pc[i * PSTR + 4];
            float av[PW] = { a.x, a.y, a.z, a.w, b.x, b.y, b.z, b.w };
            float m[PW];
            #pragma unroll
            for (int j = 0; j < PW; ++j) {
                float acc = av[j];
                #pragma unroll
                for (int t = 0; t < j; ++t) acc -= m[t] * Ublk[g][p][t][j];
                m[j] = acc * DinvAll[g][p][j];
            }
            f4 ma = { m[0], m[1], m[2], m[3] }, mb = { m[4], m[5], m[6], m[7] };
            *(f4*)&Pc[i * PSTR]     = ma;     // multipliers: GEMM lA operand
            *(f4*)&Pc[i * PSTR + 4] = mb;
            #pragma unroll
            for (int u = 0; u < PW; ++u) Up[g][u * USTR + i] = m[u] * Dd[g][u];
            float ry = rhsY[g][i], rz = rhsZ[g][i];
            #pragma unroll
            for (int t = 0; t < PW; ++t) {
                ry -= m[t] * rhsY[g][k0 + t];
                rz -= m[t] * rhsZ[g][k0 + t];
            }
            rhsY[g][i] = ry; rhsZ[g][i] = rz;
        }
        __syncthreads();
    }

    // ================= blocked back substitution (both RHS, both mols) =================
    for (int pb = NPAN - 1; pb >= 0; --pb) {
        const int k0 = PW * pb;
        if (tid < 4) {                                // 4 parallel 8x8 upper-tri solves
            const int gg = tid >> 1;
            float* rhs = (tid & 1) ? rhsZ[gg] : rhsY[gg];
            float* sx  = (tid & 1) ? sxZ[gg]  : sxY[gg];
            float x[PW];
            #pragma unroll
            for (int kk = PW - 1; kk >= 0; --kk) {
                float acc = rhs[k0 + kk];
                #pragma unroll
                for (int jj = kk + 1; jj < PW; ++jj) acc -= Ublk[gg][pb][kk][jj] * x[jj];
                x[kk] = acc * DinvAll[gg][pb][kk];
                sx[k0 + kk] = x[kk];
            }
        }
        __syncthreads();
        if (wv == (pb & 1) && lane < 4 * pb) {        // rank-8 back-update from regs
            f4 a00, a01, a10, a11;
            switch ((pb >> 1) & 7) {
                case 0:  a00 = Ar0[0];  a01 = Ar0[1];  a10 = Ar1[0];  a11 = Ar1[1];  break;
                case 1:  a00 = Ar0[2];  a01 = Ar0[3];  a10 = Ar1[2];  a11 = Ar1[3];  break;
                case 2:  a00 = Ar0[4];  a01 = Ar0[5];  a10 = Ar1[4];  a11 = Ar1[5];  break;
                case 3:  a00 = Ar0[6];  a01 = Ar0[7];  a10 = Ar1[6];  a11 = Ar1[7];  break;
                case 4:  a00 = Ar0[8];  a01 = Ar0[9];  a10 = Ar1[8];  a11 = Ar1[9];  break;
                case 5:  a00 = Ar0[10]; a01 = Ar0[11]; a10 = Ar1[10]; a11 = Ar1[11]; break;
                case 6:  a00 = Ar0[12]; a01 = Ar0[13]; a10 = Ar1[12]; a11 = Ar1[13]; break;
                default: a00 = Ar0[14]; a01 = Ar0[15]; a10 = Ar1[14]; a11 = Ar1[15]; break;
            }
            float yy0 = rhsY[g][r0], yy1 = rhsY[g][r1];
            float zz0 = rhsZ[g][r0], zz1 = rhsZ[g][r1];
            yy0 -= a00.x*sxY[g][k0]   + a00.y*sxY[g][k0+1] + a00.z*sxY[g][k0+2] + a00.w*sxY[g][k0+3]
                 + a01.x*sxY[g][k0+4] + a01.y*sxY[g][k0+5] + a01.z*sxY[g][k0+6] + a01.w*sxY[g][k0+7];
            yy1 -= a10.x*sxY[g][k0]   + a10.y*sxY[g][k0+1] + a10.z*sxY[g][k0+2] + a10.w*sxY[g][k0+3]
                 + a11.x*sxY[g][k0+4] + a11.y*sxY[g][k0+5] + a11.z*sxY[g][k0+6] + a11.w*sxY[g][k0+7];
            zz0 -= a00.x*sxZ[g][k0]   + a00.y*sxZ[g][k0+1] + a00.z*sxZ[g][k0+2] + a00.w*sxZ[g][k0+3]
                 + a01.x*sxZ[g][k0+4] + a01.y*sxZ[g][k0+5] + a01.z*sxZ[g][k0+6] + a01.w*sxZ[g][k0+7];
            zz1 -= a10.x*sxZ[g][k0]   + a10.y*sxZ[g][k0+1] + a10.z*sxZ[g][k0+2] + a10.w*sxZ[g][k0+3]
                 + a11.x*sxZ[g][k0+4] + a11.y*sxZ[g][k0+5] + a11.z*sxZ[g][k0+6] + a11.w*sxZ[g][k0+7];
            rhsY[g][r0] = yy0; rhsY[g][r1] = yy1;
            rhsZ[g][r0] = zz0; rhsZ[g][r1] = zz1;
        }
        __syncthreads();
    }

    // ---- Schur closure: lambda = (1'y - Q)/(1'z - 1); q = y - lambda z ----
    if (wv == 0) {
        float vY = sxY[g][lane] + sxY[g][lane + 64];
        float vZ = sxZ[g][lane] + sxZ[g][lane + 64];
        #pragma unroll
        for (int off = 32; off; off >>= 1) {
            vY += __shfl_xor(vY, off);
            vZ += __shfl_xor(vZ, off);
        }
        if (lane == 0) lamS[g] = (vY - total_charge[mol]) / (vZ - 1.0f);
    }
    __syncthreads();
    out[base + gt] = sxY[g][gt] - lamS[g] * sxZ[g][gt];
}

extern "C" void kernel_launch(void* const* d_in, const int* in_sizes, int n_in,
                              void* d_out, int out_size, void* d_ws, size_t ws_size,
                              hipStream_t stream) {
    const float* eneg           = (const float*)d_in[0];
    const float* positions      = (const float*)d_in[1];
    const float* node_attrs     = (const float*)d_in[2];
    const float* hardness       = (const float*)d_in[3];
    const float* total_charge   = (const float*)d_in[4];
    // d_in[5] = batch (unused: equal-sized sorted molecules)
    const int*   atomic_numbers = (const int*)d_in[6];
    float* out = (float*)d_out;

    ceq_solve_kernel<<<NMOL / 2, BLOCK, 0, stream>>>(
        eneg, positions, node_attrs, hardness, total_charge, atomic_numbers, out);
}